// Round 1
// 634.454 us; speedup vs baseline: 1.1681x; 1.1681x over previous
//
#include <hip/hip_runtime.h>
#include <hip/hip_bf16.h>
#include <stdint.h>

// Problem constants (from reference): B=4, T=2048 -> N=8192 tokens
#define N_TOK 8192
#define C_DIM 1024
#define E_NUM 8
#define H_DIM 4096
#define ROWS_PAD 9216   // 8192 + 8*128 upper bound on per-expert 128-padded rows
#define HBLK 32         // blocks in histogram/scan phase (256 tokens each)

typedef __attribute__((ext_vector_type(8))) short bf16x8;
typedef __attribute__((ext_vector_type(4))) float f32x4;

// round-to-nearest-even fp32 -> bf16
static __device__ __forceinline__ unsigned short f2bf(float f) {
    union { float f; unsigned u; } v; v.f = f;
    unsigned r = (v.u + 0x7FFFu + ((v.u >> 16) & 1u)) >> 16;
    return (unsigned short)r;
}

// async global->LDS, 16B per lane (LDS dest = wave-uniform base + lane*16)
static __device__ __forceinline__ void load_lds16(const unsigned short* g, unsigned short* l) {
    __builtin_amdgcn_global_load_lds(
        (const __attribute__((address_space(1))) unsigned int*)g,
        (__attribute__((address_space(3))) unsigned int*)l, 16, 0, 0);
}

// ---------------------------------------------------------------------------
// Transpose + cast: in [E][K][N] fp32 -> out [E][N][K] bf16.
// LDS-tiled (64n x 256k per block) so BOTH global read and write are
// coalesced 256B-per-instruction. Old version scattered 16B writes at
// 2-8KB stride (~25% line utilization on 64MB of writes per call).
// LDS row stride 258 ushorts (516B): bank = (n + k/2) mod 32 -> worst 2-way
// on the u16 writes (lane==n) and on the b32 reads (lane==dword idx) = free.
// ---------------------------------------------------------------------------
#define TP_STRIDE 258
__global__ __launch_bounds__(256) void transpose_w(const float* __restrict__ in,
                                                   unsigned short* __restrict__ out,
                                                   int K, int N) {
    __shared__ unsigned short tile[64 * TP_STRIDE];   // 33 KB
    int e  = blockIdx.z;
    int n0 = blockIdx.x * 64;
    int k0 = blockIdx.y * 256;
    int t = threadIdx.x;
    int lane = t & 63;
    int w = t >> 6;

    // phase 1: read k-rows (lanes along n, coalesced), store transposed in LDS
    const float* ip = in + (size_t)e * K * N + (size_t)k0 * N + n0 + lane;
    unsigned short* lrow = &tile[lane * TP_STRIDE];
#pragma unroll 8
    for (int i = 0; i < 64; i++) {
        int k = w * 64 + i;                       // wave w owns k rows [64w, 64w+64)
        lrow[k] = f2bf(ip[(size_t)k * N]);
    }
    __syncthreads();

    // phase 2: write n-rows (lanes along k, 256B contiguous per instruction)
    unsigned short* op = out + (size_t)e * N * K + (size_t)n0 * K + k0;
    for (int j = 0; j < 16; j++) {
        int n = w * 16 + j;                       // wave w owns n rows [16w, 16w+16)
        const unsigned* src = (const unsigned*)&tile[n * TP_STRIDE];
        unsigned* dst = (unsigned*)&op[(size_t)n * K];
        dst[lane]      = src[lane];
        dst[lane + 64] = src[lane + 64];
    }
}

// ---------------------------------------------------------------------------
// Router: one wave per token, fp64 accumulation. NO global atomics.
// ---------------------------------------------------------------------------
__global__ void router_kernel(const float* __restrict__ x, const float* __restrict__ Wr,
                              const float* __restrict__ br,
                              float* __restrict__ probs, int* __restrict__ eidx) {
    int n = blockIdx.x * 4 + (threadIdx.x >> 6);
    int lane = threadIdx.x & 63;
    const float* xr = x + (size_t)n * C_DIM;
    double acc[E_NUM];
#pragma unroll
    for (int e = 0; e < E_NUM; e++) acc[e] = 0.0;
    for (int i = 0; i < 16; i++) {
        int c = i * 64 + lane;
        float xv = xr[c];
        const float4* wr = (const float4*)(Wr + c * E_NUM);
        float4 w0 = wr[0], w1 = wr[1];
        acc[0] += (double)xv * w0.x; acc[1] += (double)xv * w0.y;
        acc[2] += (double)xv * w0.z; acc[3] += (double)xv * w0.w;
        acc[4] += (double)xv * w1.x; acc[5] += (double)xv * w1.y;
        acc[6] += (double)xv * w1.z; acc[7] += (double)xv * w1.w;
    }
#pragma unroll
    for (int e = 0; e < E_NUM; e++) {
#pragma unroll
        for (int o = 32; o > 0; o >>= 1) acc[e] += __shfl_xor(acc[e], o, 64);
    }
    if (lane == 0) {
        float l[E_NUM];
        for (int e = 0; e < E_NUM; e++) l[e] = (float)acc[e] + br[e];
        int arg = 0; float m = l[0];
        for (int e = 1; e < E_NUM; e++) if (l[e] > m) { m = l[e]; arg = e; }  // first-max
        float s = 0.f;
        for (int e = 0; e < E_NUM; e++) s += expf(l[e] - m);
        probs[n] = 1.0f / s;     // = exp(lmax-m)/sum
        eidx[n] = arg;
    }
}

// ---------------------------------------------------------------------------
// Phase 1: per-block expert histogram (LDS atomics only)
// ---------------------------------------------------------------------------
__global__ void hist_kernel(const int* __restrict__ eidx, int* __restrict__ blk_cnt) {
    __shared__ int lh[E_NUM];
    int t = threadIdx.x, b = blockIdx.x;
    if (t < E_NUM) lh[t] = 0;
    __syncthreads();
    atomicAdd(&lh[eidx[b * 256 + t]], 1);
    __syncthreads();
    if (t < E_NUM) blk_cnt[b * E_NUM + t] = lh[t];
}

// ---------------------------------------------------------------------------
// Finalize: totals, 128-padded segment offsets, per-block bases, aux loss.
// Lane-parallel: lane e owns expert e (old version was 1 thread doing ~520
// latency-serialized global ops).
// ---------------------------------------------------------------------------
__global__ void finalize_kernel(const int* __restrict__ blk_cnt, int* __restrict__ cnt,
                                int* __restrict__ seg, int* __restrict__ blockbase,
                                float* __restrict__ aux_out) {
    int e = threadIdx.x;           // 64 threads; lanes 0..7 own experts
    int c[HBLK];
    int tot = 0;
    if (e < E_NUM) {
#pragma unroll
        for (int b = 0; b < HBLK; b++) { c[b] = blk_cnt[b * E_NUM + e]; tot += c[b]; }
    }
    int pad = ((tot + 127) >> 7) << 7;
    // exclusive prefix over experts (all lanes run the shuffles)
    int sg = 0;
#pragma unroll
    for (int j = 0; j < E_NUM; j++) {
        int pj = __shfl(pad, j, 64);
        if (j < e) sg += pj;
    }
    if (e < E_NUM) {
        cnt[e] = tot;
        seg[e] = sg;
        int run = sg;
#pragma unroll
        for (int b = 0; b < HBLK; b++) { blockbase[b * E_NUM + e] = run; run += c[b]; }
        float fr = (float)tot / (float)N_TOK - 1.0f / (float)E_NUM;
        float s = fr * fr;
#pragma unroll
        for (int o = 4; o > 0; o >>= 1) s += __shfl_xor(s, o, 64);  // sum lanes 0..7
        if (e == 0) aux_out[0] = s / (float)E_NUM;
    }
}

// ---------------------------------------------------------------------------
// Phase 2: assign rows (LDS-atomic local rank + precomputed block base)
// ---------------------------------------------------------------------------
__global__ void gatherpos_kernel(const float* __restrict__ probs, const int* __restrict__ eidx,
                                 const int* __restrict__ blockbase, int* __restrict__ tok_row,
                                 int* __restrict__ inv_row, float* __restrict__ rowprob) {
    __shared__ int lh[E_NUM];
    int t = threadIdx.x, b = blockIdx.x;
    if (t < E_NUM) lh[t] = 0;
    __syncthreads();
    int n = b * 256 + t;
    int e = eidx[n];
    int lrank = atomicAdd(&lh[e], 1);
    int row = blockbase[b * E_NUM + e] + lrank;
    tok_row[n] = row;
    inv_row[row] = n;
    rowprob[row] = probs[n];
}

// ---------------------------------------------------------------------------
// Copy: cast x rows into expert-grouped bf16 buffer; one wave per token.
// float4 loads (16B/lane), uint2 stores (8B/lane).
// ---------------------------------------------------------------------------
__global__ void copy_kernel(const float* __restrict__ x, const int* __restrict__ tok_row,
                            unsigned short* __restrict__ xg) {
    int n = blockIdx.x * 4 + (threadIdx.x >> 6);
    int lane = threadIdx.x & 63;
    int row = tok_row[n];
    const float4* xr = (const float4*)(x + (size_t)n * C_DIM);
    uint2* xgr = (uint2*)(xg + (size_t)row * C_DIM);
#pragma unroll
    for (int i = 0; i < 4; i++) {
        float4 v = xr[i * 64 + lane];
        uint2 p;
        p.x = (unsigned)f2bf(v.x) | ((unsigned)f2bf(v.y) << 16);
        p.y = (unsigned)f2bf(v.z) | ((unsigned)f2bf(v.w) << 16);
        xgr[i * 64 + lane] = p;
    }
}

// ---------------------------------------------------------------------------
// Grouped GEMM, m97 structure: 128x128 tile, BK=32, 256 thr (4 waves, each
// 64x64 = 4x4 MFMA 16x16x32 tiles). A [rows,K] bf16 k-contig, Bt [E][N][K]
// bf16 k-contig. EPI=1: +bias, exact gelu, bf16 store to hg.
// EPI=2: +bias, *gate, scatter fp32 to out by inv_row.
// ---------------------------------------------------------------------------
template <int KDIM, int NDIM, int EPI>
__global__ __launch_bounds__(256) void moe_gemm(
    const unsigned short* __restrict__ Ag, const unsigned short* __restrict__ Bt,
    const float* __restrict__ bias, unsigned short* __restrict__ hg,
    float* __restrict__ out, const int* __restrict__ cnt, const int* __restrict__ seg,
    const int* __restrict__ inv_row, const float* __restrict__ rowprob) {
    // map m-slot -> (expert, m-tile)
    int mt = blockIdx.y;
    int e;
    for (e = 0; e < E_NUM; e++) {
        int te = (cnt[e] + 127) >> 7;
        if (mt < te) break;
        mt -= te;
    }
    if (e >= E_NUM) return;
    int row0 = seg[e] + mt * 128;
    int col0 = blockIdx.x * 128;

    __shared__ unsigned short As[128 * 32];
    __shared__ unsigned short Bs[128 * 32];

    const unsigned short* Ab = Ag + (size_t)row0 * KDIM;
    const unsigned short* Bb = Bt + (size_t)e * NDIM * KDIM + (size_t)col0 * KDIM;

    int tid = threadIdx.x;
    int lane = tid & 63;
    int wv = tid >> 6;
    int wr = (wv >> 1) * 64, wc = (wv & 1) * 64;

    f32x4 acc[4][4] = {};

    int srow = lane >> 2;          // 0..15: row within 16-row chunk
    int scol = (lane & 3) * 8;     // 0/8/16/24: element offset (16B)

    for (int kk = 0; kk < KDIM; kk += 32) {
#pragma unroll
        for (int r = 0; r < 2; r++) {
            int chunk = wv + 4 * r;            // 0..7, 16 rows each
            int rowa = 16 * chunk + srow;
            load_lds16(Ab + (size_t)rowa * KDIM + kk + scol, &As[16 * chunk * 32]);
            load_lds16(Bb + (size_t)rowa * KDIM + kk + scol, &Bs[16 * chunk * 32]);
        }
        __syncthreads();           // drains vmcnt (global_load_lds) + barrier
        bf16x8 af[4], bfr[4];
        int fr = lane & 15, fq = (lane >> 4) * 8;
#pragma unroll
        for (int i = 0; i < 4; i++) {
            af[i]  = *(const bf16x8*)&As[(wr + i * 16 + fr) * 32 + fq];
            bfr[i] = *(const bf16x8*)&Bs[(wc + i * 16 + fr) * 32 + fq];
        }
#pragma unroll
        for (int i = 0; i < 4; i++)
#pragma unroll
            for (int j = 0; j < 4; j++)
                acc[i][j] = __builtin_amdgcn_mfma_f32_16x16x32_bf16(af[i], bfr[j], acc[i][j], 0, 0, 0);
        __syncthreads();
    }

    // epilogue; C/D layout: col = lane&15, row = (lane>>4)*4 + reg
    int cl = lane & 15, rq = (lane >> 4) * 4;
#pragma unroll
    for (int i = 0; i < 4; i++) {
#pragma unroll
        for (int j = 0; j < 4; j++) {
            int gcol = col0 + wc + j * 16 + cl;
            float b = bias[e * NDIM + gcol];
#pragma unroll
            for (int r = 0; r < 4; r++) {
                int grow = row0 + wr + i * 16 + rq + r;
                float v = acc[i][j][r] + b;
                if (EPI == 1) {
                    v = 0.5f * v * (1.0f + erff(v * 0.70710678118654752f));  // exact gelu
                    hg[(size_t)grow * NDIM + gcol] = f2bf(v);
                } else {
                    int token = inv_row[grow];
                    if (token >= 0) out[(size_t)token * NDIM + gcol] = rowprob[grow] * v;
                }
            }
        }
    }
}

// ---------------------------------------------------------------------------
extern "C" void kernel_launch(void* const* d_in, const int* in_sizes, int n_in,
                              void* d_out, int out_size, void* d_ws, size_t ws_size,
                              hipStream_t stream) {
    const float* x  = (const float*)d_in[0];
    const float* Wr = (const float*)d_in[1];
    const float* br = (const float*)d_in[2];
    const float* W1 = (const float*)d_in[3];
    const float* b1 = (const float*)d_in[4];
    const float* W2 = (const float*)d_in[5];
    const float* b2 = (const float*)d_in[6];
    float* out = (float*)d_out;

    // workspace layout (~218.4 MB)
    char* ws = (char*)d_ws;
    unsigned short* W1t = (unsigned short*)ws;                               // [E][H][C] bf16, 64MB
    unsigned short* W2t = (unsigned short*)(ws + (64ull << 20));             // [E][C][H] bf16, 64MB
    unsigned short* xg  = (unsigned short*)(ws + (128ull << 20));            // [ROWS_PAD][C] bf16, 18MB
    unsigned short* hg  = (unsigned short*)(ws + (128ull << 20) + 18874368ull); // [ROWS_PAD][H] bf16, 72MB
    char* small = ws + (128ull << 20) + 18874368ull + 75497472ull;
    float* probs     = (float*)small;                       // 32KB
    int*   eidx      = (int*)(small + 32768);               // 32KB
    float* rowprob   = (float*)(small + 65536);             // 36KB
    int*   inv_row   = (int*)(small + 65536 + 36864);       // 36KB
    int*   tok_row   = (int*)(small + 65536 + 73728);       // 32KB
    int*   blk_cnt   = (int*)(small + 65536 + 73728 + 32768);        // 1KB
    int*   blockbase = blk_cnt + HBLK * E_NUM;                       // 1KB
    int*   cnt       = blockbase + HBLK * E_NUM;                     // 8
    int*   seg       = cnt + 8;                                      // 8

    hipMemsetAsync(xg, 0, (size_t)ROWS_PAD * C_DIM * 2, stream);          // zero pads
    hipMemsetAsync(inv_row, 0xFF, ROWS_PAD * 4, stream);                  // -1

    // W1 [E][C][H] -> W1t [E][H][C] ; W2 [E][H][C] -> W2t [E][C][H]
    transpose_w<<<dim3(H_DIM / 64, C_DIM / 256, E_NUM), 256, 0, stream>>>(W1, W1t, C_DIM, H_DIM);
    transpose_w<<<dim3(C_DIM / 64, H_DIM / 256, E_NUM), 256, 0, stream>>>(W2, W2t, H_DIM, C_DIM);

    router_kernel<<<N_TOK / 4, 256, 0, stream>>>(x, Wr, br, probs, eidx);
    hist_kernel<<<HBLK, 256, 0, stream>>>(eidx, blk_cnt);
    finalize_kernel<<<1, 64, 0, stream>>>(blk_cnt, cnt, seg, blockbase,
                                          out + (size_t)N_TOK * C_DIM);
    gatherpos_kernel<<<HBLK, 256, 0, stream>>>(probs, eidx, blockbase, tok_row, inv_row, rowprob);
    copy_kernel<<<N_TOK / 4, 256, 0, stream>>>(x, tok_row, xg);

    // GEMM1: h = gelu(xg @ W1[e] + b1[e])   [rows x H], K=C
    moe_gemm<C_DIM, H_DIM, 1><<<dim3(H_DIM / 128, 72), 256, 0, stream>>>(
        xg, W1t, b1, hg, nullptr, cnt, seg, inv_row, rowprob);
    // GEMM2: out[token] = prob * (hg @ W2[e] + b2[e])   [rows x C], K=H
    moe_gemm<H_DIM, C_DIM, 2><<<dim3(C_DIM / 128, 72), 256, 0, stream>>>(
        hg, W2t, b2, nullptr, out, cnt, seg, inv_row, rowprob);
}

// Round 2
// 616.753 us; speedup vs baseline: 1.2016x; 1.0287x over previous
//
#include <hip/hip_runtime.h>
#include <hip/hip_bf16.h>
#include <stdint.h>

// Problem constants (from reference): B=4, T=2048 -> N=8192 tokens
#define N_TOK 8192
#define C_DIM 1024
#define E_NUM 8
#define H_DIM 4096
#define ROWS_PAD 10240  // 8192 + 8*256 upper bound on per-expert 256-padded rows
#define HBLK 32         // blocks in histogram/scan phase (256 tokens each)
#define MT_MAX 40       // max total 256-row m-tiles = 8192/256 + 8

typedef __attribute__((ext_vector_type(8))) short bf16x8;
typedef __attribute__((ext_vector_type(4))) float f32x4;

// round-to-nearest-even fp32 -> bf16
static __device__ __forceinline__ unsigned short f2bf(float f) {
    union { float f; unsigned u; } v; v.f = f;
    unsigned r = (v.u + 0x7FFFu + ((v.u >> 16) & 1u)) >> 16;
    return (unsigned short)r;
}

// async global->LDS, 16B per lane (LDS dest = wave-uniform base + lane*16)
static __device__ __forceinline__ void load_lds16(const unsigned short* g, unsigned short* l) {
    __builtin_amdgcn_global_load_lds(
        (const __attribute__((address_space(1))) unsigned int*)g,
        (__attribute__((address_space(3))) unsigned int*)l, 16, 0, 0);
}

// swizzled fragment read from a [128 rows][64 k] bf16 half-buffer.
// linear byte = r*128 + ks*64 + hi*16 ; swizzle: unit ^= (r&7)  (T2, G4 formula)
static __device__ __forceinline__ bf16x8 rfrag(const unsigned short* hb, int r, int ks, int hi) {
    int byte = r * 128 + ks * 64 + hi * 16;
    byte ^= (r & 7) << 4;
    return *(const bf16x8*)((const char*)hb + byte);
}

// ---------------------------------------------------------------------------
// Transpose + cast: in [E][K][N] fp32 -> out [E][N][K] bf16. LDS-tiled.
// ---------------------------------------------------------------------------
#define TP_STRIDE 258
__global__ __launch_bounds__(256) void transpose_w(const float* __restrict__ in,
                                                   unsigned short* __restrict__ out,
                                                   int K, int N) {
    __shared__ unsigned short tile[64 * TP_STRIDE];   // 33 KB
    int e  = blockIdx.z;
    int n0 = blockIdx.x * 64;
    int k0 = blockIdx.y * 256;
    int t = threadIdx.x;
    int lane = t & 63;
    int w = t >> 6;

    const float* ip = in + (size_t)e * K * N + (size_t)k0 * N + n0 + lane;
    unsigned short* lrow = &tile[lane * TP_STRIDE];
#pragma unroll 8
    for (int i = 0; i < 64; i++) {
        int k = w * 64 + i;
        lrow[k] = f2bf(ip[(size_t)k * N]);
    }
    __syncthreads();

    unsigned short* op = out + (size_t)e * N * K + (size_t)n0 * K + k0;
    for (int j = 0; j < 16; j++) {
        int n = w * 16 + j;
        const unsigned* src = (const unsigned*)&tile[n * TP_STRIDE];
        unsigned* dst = (unsigned*)&op[(size_t)n * K];
        dst[lane]      = src[lane];
        dst[lane + 64] = src[lane + 64];
    }
}

// ---------------------------------------------------------------------------
// Router: one wave per token, fp64 accumulation. NO global atomics.
// ---------------------------------------------------------------------------
__global__ void router_kernel(const float* __restrict__ x, const float* __restrict__ Wr,
                              const float* __restrict__ br,
                              float* __restrict__ probs, int* __restrict__ eidx) {
    int n = blockIdx.x * 4 + (threadIdx.x >> 6);
    int lane = threadIdx.x & 63;
    const float* xr = x + (size_t)n * C_DIM;
    double acc[E_NUM];
#pragma unroll
    for (int e = 0; e < E_NUM; e++) acc[e] = 0.0;
    for (int i = 0; i < 16; i++) {
        int c = i * 64 + lane;
        float xv = xr[c];
        const float4* wr = (const float4*)(Wr + c * E_NUM);
        float4 w0 = wr[0], w1 = wr[1];
        acc[0] += (double)xv * w0.x; acc[1] += (double)xv * w0.y;
        acc[2] += (double)xv * w0.z; acc[3] += (double)xv * w0.w;
        acc[4] += (double)xv * w1.x; acc[5] += (double)xv * w1.y;
        acc[6] += (double)xv * w1.z; acc[7] += (double)xv * w1.w;
    }
#pragma unroll
    for (int e = 0; e < E_NUM; e++) {
#pragma unroll
        for (int o = 32; o > 0; o >>= 1) acc[e] += __shfl_xor(acc[e], o, 64);
    }
    if (lane == 0) {
        float l[E_NUM];
        for (int e = 0; e < E_NUM; e++) l[e] = (float)acc[e] + br[e];
        int arg = 0; float m = l[0];
        for (int e = 1; e < E_NUM; e++) if (l[e] > m) { m = l[e]; arg = e; }  // first-max
        float s = 0.f;
        for (int e = 0; e < E_NUM; e++) s += expf(l[e] - m);
        probs[n] = 1.0f / s;     // = exp(lmax-m)/sum
        eidx[n] = arg;
    }
}

// ---------------------------------------------------------------------------
// Phase 1: per-block expert histogram (LDS atomics only)
// ---------------------------------------------------------------------------
__global__ void hist_kernel(const int* __restrict__ eidx, int* __restrict__ blk_cnt) {
    __shared__ int lh[E_NUM];
    int t = threadIdx.x, b = blockIdx.x;
    if (t < E_NUM) lh[t] = 0;
    __syncthreads();
    atomicAdd(&lh[eidx[b * 256 + t]], 1);
    __syncthreads();
    if (t < E_NUM) blk_cnt[b * E_NUM + t] = lh[t];
}

// ---------------------------------------------------------------------------
// Finalize: totals, 256-padded segment offsets, per-block bases, aux loss.
// Lane-parallel: lane e owns expert e.
// ---------------------------------------------------------------------------
__global__ void finalize_kernel(const int* __restrict__ blk_cnt, int* __restrict__ cnt,
                                int* __restrict__ seg, int* __restrict__ blockbase,
                                float* __restrict__ aux_out) {
    int e = threadIdx.x;           // 64 threads; lanes 0..7 own experts
    int c[HBLK];
    int tot = 0;
    if (e < E_NUM) {
#pragma unroll
        for (int b = 0; b < HBLK; b++) { c[b] = blk_cnt[b * E_NUM + e]; tot += c[b]; }
    }
    int pad = ((tot + 255) >> 8) << 8;     // 256-pad for the 256-row GEMM tiles
    int sg = 0;
#pragma unroll
    for (int j = 0; j < E_NUM; j++) {
        int pj = __shfl(pad, j, 64);
        if (j < e) sg += pj;
    }
    if (e < E_NUM) {
        cnt[e] = tot;
        seg[e] = sg;
        int run = sg;
#pragma unroll
        for (int b = 0; b < HBLK; b++) { blockbase[b * E_NUM + e] = run; run += c[b]; }
        float fr = (float)tot / (float)N_TOK - 1.0f / (float)E_NUM;
        float s = fr * fr;
#pragma unroll
        for (int o = 4; o > 0; o >>= 1) s += __shfl_xor(s, o, 64);
        if (e == 0) aux_out[0] = s / (float)E_NUM;
    }
}

// ---------------------------------------------------------------------------
// Phase 2: assign rows (LDS-atomic local rank + precomputed block base)
// ---------------------------------------------------------------------------
__global__ void gatherpos_kernel(const float* __restrict__ probs, const int* __restrict__ eidx,
                                 const int* __restrict__ blockbase, int* __restrict__ tok_row,
                                 int* __restrict__ inv_row, float* __restrict__ rowprob) {
    __shared__ int lh[E_NUM];
    int t = threadIdx.x, b = blockIdx.x;
    if (t < E_NUM) lh[t] = 0;
    __syncthreads();
    int n = b * 256 + t;
    int e = eidx[n];
    int lrank = atomicAdd(&lh[e], 1);
    int row = blockbase[b * E_NUM + e] + lrank;
    tok_row[n] = row;
    inv_row[row] = n;
    rowprob[row] = probs[n];
}

// ---------------------------------------------------------------------------
// Copy: cast x rows into expert-grouped bf16 buffer; one wave per token.
// ---------------------------------------------------------------------------
__global__ void copy_kernel(const float* __restrict__ x, const int* __restrict__ tok_row,
                            unsigned short* __restrict__ xg) {
    int n = blockIdx.x * 4 + (threadIdx.x >> 6);
    int lane = threadIdx.x & 63;
    int row = tok_row[n];
    const float4* xr = (const float4*)(x + (size_t)n * C_DIM);
    uint2* xgr = (uint2*)(xg + (size_t)row * C_DIM);
#pragma unroll
    for (int i = 0; i < 4; i++) {
        float4 v = xr[i * 64 + lane];
        uint2 p;
        p.x = (unsigned)f2bf(v.x) | ((unsigned)f2bf(v.y) << 16);
        p.y = (unsigned)f2bf(v.z) | ((unsigned)f2bf(v.w) << 16);
        xgr[i * 64 + lane] = p;
    }
}

// ---------------------------------------------------------------------------
// Grouped GEMM, 256x256 8-phase template (T2 swizzle + T3/T4 counted vmcnt +
// T5 setprio). BK=64, 512 thr = 8 waves (2M x 4N), per-wave 128x64 output.
// LDS 128KB: [dbuf][A/B][half][128x64] bf16, double-buffered, half-tile
// granular staging via global_load_lds (linear LDS dest, inverse-swizzled
// global source; reads apply unit ^= row&7 swizzle -> 2-lane/bank = free).
// Phases per K-tile: q0(mh0,nh0: 12 ds_reads) q1(mh0,nh1: 4) q2(mh1,nh0: 8)
// q3(mh1,nh1: 0). m/n-frags interleave halves (row = mh*128 + wm*64 + i*16)
// so each half is read in exactly one phase; stages that overwrite the live
// buffer issue only after that half's last-reader phase end-barrier.
// Pipeline 2 tiles deep: stage q0 -> B0[t+1], q1 -> A0[t+2], q2 -> B1[t+2],
// q3 -> A1[t+2]; vmcnt(6) once per K-tile at q3 (3 halves stay in flight).
// ---------------------------------------------------------------------------
#define STAGE(d, ab, h, G, kt) do {                                            \
    _Pragma("unroll")                                                          \
    for (int i_ = 0; i_ < 2; i_++) {                                           \
        int idx_ = i_ * 512 + tid;                                             \
        int row_ = idx_ >> 3;                                                  \
        int us_ = (idx_ & 7) ^ (row_ & 7);                                     \
        load_lds16((G) + (size_t)((h) * 128 + row_) * KDIM + (kt) * 64 + us_ * 8, \
                   &lds[d][ab][h][(i_ * 512 + (tid & ~63)) * 8]);              \
    } } while (0)

#define PHASE(D, MH, NH, LA, LB, STAGE_STMT, WAIT_STMT) do {                   \
    if (LA) {                                                                  \
        _Pragma("unroll")                                                      \
        for (int i_ = 0; i_ < 4; i_++) {                                       \
            int r_ = wm * 64 + i_ * 16 + (lane & 15);                          \
            af[i_][0] = rfrag(&lds[D][0][MH][0], r_, 0, hi);                   \
            af[i_][1] = rfrag(&lds[D][0][MH][0], r_, 1, hi);                   \
        }                                                                      \
    }                                                                          \
    if (LB) {                                                                  \
        _Pragma("unroll")                                                      \
        for (int j_ = 0; j_ < 2; j_++) {                                       \
            int c_ = wn * 32 + j_ * 16 + (lane & 15);                          \
            bf[NH][j_][0] = rfrag(&lds[D][1][NH][0], c_, 0, hi);               \
            bf[NH][j_][1] = rfrag(&lds[D][1][NH][0], c_, 1, hi);               \
        }                                                                      \
    }                                                                          \
    STAGE_STMT;                                                                \
    __builtin_amdgcn_s_barrier();                                              \
    asm volatile("s_waitcnt lgkmcnt(0)" ::: "memory");                         \
    __builtin_amdgcn_s_setprio(1);                                             \
    _Pragma("unroll")                                                          \
    for (int i_ = 0; i_ < 4; i_++) {                                           \
        _Pragma("unroll")                                                      \
        for (int j_ = 0; j_ < 2; j_++) {                                       \
            acc[MH][i_][NH][j_] = __builtin_amdgcn_mfma_f32_16x16x32_bf16(     \
                af[i_][0], bf[NH][j_][0], acc[MH][i_][NH][j_], 0, 0, 0);       \
            acc[MH][i_][NH][j_] = __builtin_amdgcn_mfma_f32_16x16x32_bf16(     \
                af[i_][1], bf[NH][j_][1], acc[MH][i_][NH][j_], 0, 0, 0);       \
        }                                                                      \
    }                                                                          \
    __builtin_amdgcn_s_setprio(0);                                             \
    WAIT_STMT;                                                                 \
    __builtin_amdgcn_s_barrier();                                              \
} while (0)

template <int KDIM, int NDIM, int EPI>
__global__ __launch_bounds__(512) void moe_gemm(
    const unsigned short* __restrict__ Ag, const unsigned short* __restrict__ Bt,
    const float* __restrict__ bias, unsigned short* __restrict__ hg,
    float* __restrict__ out, const int* __restrict__ cnt, const int* __restrict__ seg,
    const int* __restrict__ inv_row, const float* __restrict__ rowprob) {
    // map m-slot -> (expert, m-tile)
    int mt = blockIdx.y;
    int e;
    for (e = 0; e < E_NUM; e++) {
        int te = (cnt[e] + 255) >> 8;
        if (mt < te) break;
        mt -= te;
    }
    if (e >= E_NUM) return;
    int row0 = seg[e] + mt * 256;
    int col0 = blockIdx.x * 256;

    __shared__ unsigned short lds[2][2][2][128 * 64];   // 128 KB

    const unsigned short* Ab = Ag + (size_t)row0 * KDIM;
    const unsigned short* Bb = Bt + (size_t)e * NDIM * KDIM + (size_t)col0 * KDIM;

    int tid = threadIdx.x;
    int lane = tid & 63;
    int wv = tid >> 6;
    int wm = wv >> 2;        // 0..1
    int wn = wv & 3;         // 0..3
    int hi = lane >> 4;      // 0..3

    f32x4 acc[2][4][2][2] = {};    // [MH][i][NH][j]
    bf16x8 af[4][2], bf[2][2][2];  // af[i][ks], bf[NH][j][ks]

    const int NT = KDIM / 64;

    // prologue: tile0 all 4 halves + tile1 {A0, B1, A1} (B0[1] staged at t0.q0)
    STAGE(0, 0, 0, Ab, 0);
    STAGE(0, 0, 1, Ab, 0);
    STAGE(0, 1, 0, Bb, 0);
    STAGE(0, 1, 1, Bb, 0);
    STAGE(1, 0, 0, Ab, 1);
    STAGE(1, 1, 1, Bb, 1);
    STAGE(1, 0, 1, Ab, 1);
    asm volatile("s_waitcnt vmcnt(6)" ::: "memory");   // tile0 landed, 3 halves in flight
    __builtin_amdgcn_s_barrier();

    for (int t = 0; t < NT; t++) {
        int d = t & 1, dn = d ^ 1;
        bool s1 = (t + 1 < NT), s2 = (t + 2 < NT);
        PHASE(d, 0, 0, 1, 1, { if (s1) STAGE(dn, 1, 0, Bb, t + 1); }, {});
        PHASE(d, 0, 1, 0, 1, { if (s2) STAGE(d, 0, 0, Ab, t + 2); }, {});
        PHASE(d, 1, 0, 1, 0, { if (s2) STAGE(d, 1, 1, Bb, t + 2); }, {});
        PHASE(d, 1, 1, 0, 0, { if (s2) STAGE(d, 0, 1, Ab, t + 2); },
              { if (s2)      { asm volatile("s_waitcnt vmcnt(6)" ::: "memory"); }
                else if (s1) { asm volatile("s_waitcnt vmcnt(0)" ::: "memory"); } });
    }

    // epilogue; C/D layout: col = lane&15, row = (lane>>4)*4 + reg
    int cl = lane & 15, rq = (lane >> 4) << 2;
#pragma unroll
    for (int MH = 0; MH < 2; MH++)
#pragma unroll
    for (int i = 0; i < 4; i++)
#pragma unroll
    for (int NH = 0; NH < 2; NH++)
#pragma unroll
    for (int j = 0; j < 2; j++) {
        int gcol = col0 + NH * 128 + wn * 32 + j * 16 + cl;
        float b = bias[e * NDIM + gcol];
        int growb = row0 + MH * 128 + wm * 64 + i * 16 + rq;
#pragma unroll
        for (int r = 0; r < 4; r++) {
            int grow = growb + r;
            float v = acc[MH][i][NH][j][r] + b;
            if (EPI == 1) {
                v = 0.5f * v * (1.0f + erff(v * 0.70710678118654752f));  // exact gelu
                hg[(size_t)grow * NDIM + gcol] = f2bf(v);
            } else {
                int token = inv_row[grow];
                if (token >= 0) out[(size_t)token * NDIM + gcol] = rowprob[grow] * v;
            }
        }
    }
}

// ---------------------------------------------------------------------------
extern "C" void kernel_launch(void* const* d_in, const int* in_sizes, int n_in,
                              void* d_out, int out_size, void* d_ws, size_t ws_size,
                              hipStream_t stream) {
    const float* x  = (const float*)d_in[0];
    const float* Wr = (const float*)d_in[1];
    const float* br = (const float*)d_in[2];
    const float* W1 = (const float*)d_in[3];
    const float* b1 = (const float*)d_in[4];
    const float* W2 = (const float*)d_in[5];
    const float* b2 = (const float*)d_in[6];
    float* out = (float*)d_out;

    // workspace layout (~228.2 MB)
    char* ws = (char*)d_ws;
    unsigned short* W1t = (unsigned short*)ws;                        // [E][H][C] bf16, 64MB
    unsigned short* W2t = (unsigned short*)(ws + 67108864ull);        // [E][C][H] bf16, 64MB
    unsigned short* xg  = (unsigned short*)(ws + 134217728ull);       // [ROWS_PAD][C] bf16, 20MB
    unsigned short* hg  = (unsigned short*)(ws + 155189248ull);       // [ROWS_PAD][H] bf16, 80MB
    char* small = ws + 239075328ull;
    float* probs     = (float*)small;                        // 32KB
    int*   eidx      = (int*)(small + 32768);                // 32KB
    float* rowprob   = (float*)(small + 65536);              // 40KB
    int*   inv_row   = (int*)(small + 106496);               // 40KB
    int*   tok_row   = (int*)(small + 147456);               // 32KB
    int*   blk_cnt   = (int*)(small + 180224);               // 1KB
    int*   blockbase = blk_cnt + HBLK * E_NUM;               // 1KB
    int*   cnt       = blockbase + HBLK * E_NUM;             // 8
    int*   seg       = cnt + 8;                              // 8

    hipMemsetAsync(xg, 0, (size_t)ROWS_PAD * C_DIM * 2, stream);          // zero pads
    hipMemsetAsync(inv_row, 0xFF, ROWS_PAD * 4, stream);                  // -1

    // W1 [E][C][H] -> W1t [E][H][C] ; W2 [E][H][C] -> W2t [E][C][H]
    transpose_w<<<dim3(H_DIM / 64, C_DIM / 256, E_NUM), 256, 0, stream>>>(W1, W1t, C_DIM, H_DIM);
    transpose_w<<<dim3(C_DIM / 64, H_DIM / 256, E_NUM), 256, 0, stream>>>(W2, W2t, H_DIM, C_DIM);

    router_kernel<<<N_TOK / 4, 256, 0, stream>>>(x, Wr, br, probs, eidx);
    hist_kernel<<<HBLK, 256, 0, stream>>>(eidx, blk_cnt);
    finalize_kernel<<<1, 64, 0, stream>>>(blk_cnt, cnt, seg, blockbase,
                                          out + (size_t)N_TOK * C_DIM);
    gatherpos_kernel<<<HBLK, 256, 0, stream>>>(probs, eidx, blockbase, tok_row, inv_row, rowprob);
    copy_kernel<<<N_TOK / 4, 256, 0, stream>>>(x, tok_row, xg);

    // GEMM1: h = gelu(xg @ W1[e] + b1[e])   [rows x H], K=C
    moe_gemm<C_DIM, H_DIM, 1><<<dim3(H_DIM / 256, MT_MAX), 512, 0, stream>>>(
        xg, W1t, b1, hg, nullptr, cnt, seg, inv_row, rowprob);
    // GEMM2: out[token] = prob * (hg @ W2[e] + b2[e])   [rows x C], K=H
    moe_gemm<H_DIM, C_DIM, 2><<<dim3(C_DIM / 256, MT_MAX), 512, 0, stream>>>(
        hg, W2t, b2, nullptr, out, cnt, seg, inv_row, rowprob);
}

// Round 3
// 615.709 us; speedup vs baseline: 1.2037x; 1.0017x over previous
//
#include <hip/hip_runtime.h>
#include <hip/hip_bf16.h>
#include <stdint.h>

// Problem constants (from reference): B=4, T=2048 -> N=8192 tokens
#define N_TOK 8192
#define C_DIM 1024
#define E_NUM 8
#define H_DIM 4096
#define ROWS_PAD 10240  // 8192 + 8*256 upper bound on per-expert 256-padded rows
#define HBLK 32         // blocks in histogram/scan phase (256 tokens each)
#define MT_MAX 40       // max total 256-row m-tiles = 8192/256 + 8

typedef __attribute__((ext_vector_type(8))) short bf16x8;
typedef __attribute__((ext_vector_type(4))) float f32x4;

// round-to-nearest-even fp32 -> bf16
static __device__ __forceinline__ unsigned short f2bf(float f) {
    union { float f; unsigned u; } v; v.f = f;
    unsigned r = (v.u + 0x7FFFu + ((v.u >> 16) & 1u)) >> 16;
    return (unsigned short)r;
}

// async global->LDS, 16B per lane (LDS dest = wave-uniform base + lane*16)
static __device__ __forceinline__ void load_lds16(const unsigned short* g, unsigned short* l) {
    __builtin_amdgcn_global_load_lds(
        (const __attribute__((address_space(1))) unsigned int*)g,
        (__attribute__((address_space(3))) unsigned int*)l, 16, 0, 0);
}

// swizzled fragment read from a [128 rows][64 k] bf16 half-buffer.
// linear byte = r*128 + ks*64 + hi*16 ; swizzle: unit ^= (r&7)  (T2, G4 formula)
static __device__ __forceinline__ bf16x8 rfrag(const unsigned short* hb, int r, int ks, int hi) {
    int byte = r * 128 + ks * 64 + hi * 16;
    byte ^= (r & 7) << 4;
    return *(const bf16x8*)((const char*)hb + byte);
}

// ---------------------------------------------------------------------------
// Transpose + cast: in [E][K][N] fp32 -> out [E][N][K] bf16. LDS-tiled.
// ---------------------------------------------------------------------------
#define TP_STRIDE 258
__global__ __launch_bounds__(256) void transpose_w(const float* __restrict__ in,
                                                   unsigned short* __restrict__ out,
                                                   int K, int N) {
    __shared__ unsigned short tile[64 * TP_STRIDE];   // 33 KB
    int e  = blockIdx.z;
    int n0 = blockIdx.x * 64;
    int k0 = blockIdx.y * 256;
    int t = threadIdx.x;
    int lane = t & 63;
    int w = t >> 6;

    const float* ip = in + (size_t)e * K * N + (size_t)k0 * N + n0 + lane;
    unsigned short* lrow = &tile[lane * TP_STRIDE];
#pragma unroll 8
    for (int i = 0; i < 64; i++) {
        int k = w * 64 + i;
        lrow[k] = f2bf(ip[(size_t)k * N]);
    }
    __syncthreads();

    unsigned short* op = out + (size_t)e * N * K + (size_t)n0 * K + k0;
    for (int j = 0; j < 16; j++) {
        int n = w * 16 + j;
        const unsigned* src = (const unsigned*)&tile[n * TP_STRIDE];
        unsigned* dst = (unsigned*)&op[(size_t)n * K];
        dst[lane]      = src[lane];
        dst[lane + 64] = src[lane + 64];
    }
}

// ---------------------------------------------------------------------------
// Router: one wave per token, fp64 accumulation. NO global atomics.
// ---------------------------------------------------------------------------
__global__ void router_kernel(const float* __restrict__ x, const float* __restrict__ Wr,
                              const float* __restrict__ br,
                              float* __restrict__ probs, int* __restrict__ eidx) {
    int n = blockIdx.x * 4 + (threadIdx.x >> 6);
    int lane = threadIdx.x & 63;
    const float* xr = x + (size_t)n * C_DIM;
    double acc[E_NUM];
#pragma unroll
    for (int e = 0; e < E_NUM; e++) acc[e] = 0.0;
    for (int i = 0; i < 16; i++) {
        int c = i * 64 + lane;
        float xv = xr[c];
        const float4* wr = (const float4*)(Wr + c * E_NUM);
        float4 w0 = wr[0], w1 = wr[1];
        acc[0] += (double)xv * w0.x; acc[1] += (double)xv * w0.y;
        acc[2] += (double)xv * w0.z; acc[3] += (double)xv * w0.w;
        acc[4] += (double)xv * w1.x; acc[5] += (double)xv * w1.y;
        acc[6] += (double)xv * w1.z; acc[7] += (double)xv * w1.w;
    }
#pragma unroll
    for (int e = 0; e < E_NUM; e++) {
#pragma unroll
        for (int o = 32; o > 0; o >>= 1) acc[e] += __shfl_xor(acc[e], o, 64);
    }
    if (lane == 0) {
        float l[E_NUM];
        for (int e = 0; e < E_NUM; e++) l[e] = (float)acc[e] + br[e];
        int arg = 0; float m = l[0];
        for (int e = 1; e < E_NUM; e++) if (l[e] > m) { m = l[e]; arg = e; }  // first-max
        float s = 0.f;
        for (int e = 0; e < E_NUM; e++) s += expf(l[e] - m);
        probs[n] = 1.0f / s;     // = exp(lmax-m)/sum
        eidx[n] = arg;
    }
}

// ---------------------------------------------------------------------------
// Phase 1: per-block expert histogram (LDS atomics only)
// ---------------------------------------------------------------------------
__global__ void hist_kernel(const int* __restrict__ eidx, int* __restrict__ blk_cnt) {
    __shared__ int lh[E_NUM];
    int t = threadIdx.x, b = blockIdx.x;
    if (t < E_NUM) lh[t] = 0;
    __syncthreads();
    atomicAdd(&lh[eidx[b * 256 + t]], 1);
    __syncthreads();
    if (t < E_NUM) blk_cnt[b * E_NUM + t] = lh[t];
}

// ---------------------------------------------------------------------------
// Finalize: totals, 256-padded segment offsets, per-block bases, aux loss.
// ---------------------------------------------------------------------------
__global__ void finalize_kernel(const int* __restrict__ blk_cnt, int* __restrict__ cnt,
                                int* __restrict__ seg, int* __restrict__ blockbase,
                                float* __restrict__ aux_out) {
    int e = threadIdx.x;           // 64 threads; lanes 0..7 own experts
    int c[HBLK];
    int tot = 0;
    if (e < E_NUM) {
#pragma unroll
        for (int b = 0; b < HBLK; b++) { c[b] = blk_cnt[b * E_NUM + e]; tot += c[b]; }
    }
    int pad = ((tot + 255) >> 8) << 8;     // 256-pad for the 256-row GEMM tiles
    int sg = 0;
#pragma unroll
    for (int j = 0; j < E_NUM; j++) {
        int pj = __shfl(pad, j, 64);
        if (j < e) sg += pj;
    }
    if (e < E_NUM) {
        cnt[e] = tot;
        seg[e] = sg;
        int run = sg;
#pragma unroll
        for (int b = 0; b < HBLK; b++) { blockbase[b * E_NUM + e] = run; run += c[b]; }
        float fr = (float)tot / (float)N_TOK - 1.0f / (float)E_NUM;
        float s = fr * fr;
#pragma unroll
        for (int o = 4; o > 0; o >>= 1) s += __shfl_xor(s, o, 64);
        if (e == 0) aux_out[0] = s / (float)E_NUM;
    }
}

// ---------------------------------------------------------------------------
// Phase 2: assign rows (LDS-atomic local rank + precomputed block base)
// ---------------------------------------------------------------------------
__global__ void gatherpos_kernel(const float* __restrict__ probs, const int* __restrict__ eidx,
                                 const int* __restrict__ blockbase, int* __restrict__ tok_row,
                                 int* __restrict__ inv_row, float* __restrict__ rowprob) {
    __shared__ int lh[E_NUM];
    int t = threadIdx.x, b = blockIdx.x;
    if (t < E_NUM) lh[t] = 0;
    __syncthreads();
    int n = b * 256 + t;
    int e = eidx[n];
    int lrank = atomicAdd(&lh[e], 1);
    int row = blockbase[b * E_NUM + e] + lrank;
    tok_row[n] = row;
    inv_row[row] = n;
    rowprob[row] = probs[n];
}

// ---------------------------------------------------------------------------
// Copy: cast x rows into expert-grouped bf16 buffer; one wave per token.
// ---------------------------------------------------------------------------
__global__ void copy_kernel(const float* __restrict__ x, const int* __restrict__ tok_row,
                            unsigned short* __restrict__ xg) {
    int n = blockIdx.x * 4 + (threadIdx.x >> 6);
    int lane = threadIdx.x & 63;
    int row = tok_row[n];
    const float4* xr = (const float4*)(x + (size_t)n * C_DIM);
    uint2* xgr = (uint2*)(xg + (size_t)row * C_DIM);
#pragma unroll
    for (int i = 0; i < 4; i++) {
        float4 v = xr[i * 64 + lane];
        uint2 p;
        p.x = (unsigned)f2bf(v.x) | ((unsigned)f2bf(v.y) << 16);
        p.y = (unsigned)f2bf(v.z) | ((unsigned)f2bf(v.w) << 16);
        xgr[i * 64 + lane] = p;
    }
}

// ---------------------------------------------------------------------------
// Grouped GEMM, 256x256 8-phase template. KEY CHANGE vs round 2: the K-loop
// processes 2 K-tiles per iteration with ALL-LITERAL lds buffer indices
// (m201's "8 phases/iter, 2 K-tiles/iter"). With runtime d=t&1, the waitcnt
// pass cannot prove DMA-write vs ds_read disjointness and inserts vmcnt
// drains every phase, degenerating the pipeline to 2-phase (round-2 == round-1
// perf). Literal indices make intervals provably disjoint so the counted
// vmcnt(6) survives (T4). Schedule per tile t (buf d): q0 reads{A0,B0} stages
// B0[d^1]<-t+1; q1 reads B1, stages A0[d]<-t+2; q2 reads A1, stages B1[d]<-t+2;
// q3 stages A1[d]<-t+2, vmcnt. Steady state: 14 loads outstanding at q3/q7
// wait -> vmcnt(6) pops exactly the next tile's 4 halves.
// ---------------------------------------------------------------------------
#define STAGE(d, ab, h, G, kt) do {                                            \
    _Pragma("unroll")                                                          \
    for (int i_ = 0; i_ < 2; i_++) {                                           \
        int idx_ = i_ * 512 + tid;                                             \
        int row_ = idx_ >> 3;                                                  \
        int us_ = (idx_ & 7) ^ (row_ & 7);                                     \
        load_lds16((G) + (size_t)((h) * 128 + row_) * KDIM + (kt) * 64 + us_ * 8, \
                   &lds[d][ab][h][(i_ * 512 + (tid & ~63)) * 8]);              \
    } } while (0)

#define FRAG_A(D, MH) do {                                                     \
    _Pragma("unroll")                                                          \
    for (int i_ = 0; i_ < 4; i_++) {                                           \
        int r_ = wm * 64 + i_ * 16 + (lane & 15);                              \
        af[i_][0] = rfrag(&lds[D][0][MH][0], r_, 0, hi);                       \
        af[i_][1] = rfrag(&lds[D][0][MH][0], r_, 1, hi);                       \
    } } while (0)

#define FRAG_B(D, NH) do {                                                     \
    _Pragma("unroll")                                                          \
    for (int j_ = 0; j_ < 2; j_++) {                                           \
        int c_ = wn * 32 + j_ * 16 + (lane & 15);                              \
        bf[NH][j_][0] = rfrag(&lds[D][1][NH][0], c_, 0, hi);                   \
        bf[NH][j_][1] = rfrag(&lds[D][1][NH][0], c_, 1, hi);                   \
    } } while (0)

#define MMAQ(MH, NH) do {                                                      \
    __builtin_amdgcn_s_setprio(1);                                             \
    _Pragma("unroll")                                                          \
    for (int i_ = 0; i_ < 4; i_++) {                                           \
        _Pragma("unroll")                                                      \
        for (int j_ = 0; j_ < 2; j_++) {                                       \
            acc[MH][i_][NH][j_] = __builtin_amdgcn_mfma_f32_16x16x32_bf16(     \
                af[i_][0], bf[NH][j_][0], acc[MH][i_][NH][j_], 0, 0, 0);       \
            acc[MH][i_][NH][j_] = __builtin_amdgcn_mfma_f32_16x16x32_bf16(     \
                af[i_][1], bf[NH][j_][1], acc[MH][i_][NH][j_], 0, 0, 0);       \
        }                                                                      \
    }                                                                          \
    __builtin_amdgcn_s_setprio(0);                                             \
} while (0)

#define BAR()   __builtin_amdgcn_s_barrier()
#define LGKM0() do { asm volatile("s_waitcnt lgkmcnt(0)" ::: "memory");        \
                     __builtin_amdgcn_sched_barrier(0); } while (0)
#define LGKM8() asm volatile("s_waitcnt lgkmcnt(8)" ::: "memory")
#define VM6()   asm volatile("s_waitcnt vmcnt(6)" ::: "memory")
#define VM0()   asm volatile("s_waitcnt vmcnt(0)" ::: "memory")

template <int KDIM, int NDIM, int EPI>
__global__ __launch_bounds__(512) void moe_gemm(
    const unsigned short* __restrict__ Ag, const unsigned short* __restrict__ Bt,
    const float* __restrict__ bias, unsigned short* __restrict__ hg,
    float* __restrict__ out, const int* __restrict__ cnt, const int* __restrict__ seg,
    const int* __restrict__ inv_row, const float* __restrict__ rowprob) {
    // map m-slot -> (expert, m-tile)
    int mt = blockIdx.y;
    int e;
    for (e = 0; e < E_NUM; e++) {
        int te = (cnt[e] + 255) >> 8;
        if (mt < te) break;
        mt -= te;
    }
    if (e >= E_NUM) return;
    int row0 = seg[e] + mt * 256;
    int col0 = blockIdx.x * 256;

    __shared__ unsigned short lds[2][2][2][128 * 64];   // 128 KB

    const unsigned short* Ab = Ag + (size_t)row0 * KDIM;
    const unsigned short* Bb = Bt + (size_t)e * NDIM * KDIM + (size_t)col0 * KDIM;

    int tid = threadIdx.x;
    int lane = tid & 63;
    int wv = tid >> 6;
    int wm = wv >> 2;        // 0..1
    int wn = wv & 3;         // 0..3
    int hi = lane >> 4;      // 0..3

    f32x4 acc[2][4][2][2] = {};    // [MH][i][NH][j]
    bf16x8 af[4][2], bf[2][2][2];  // af[i][ks], bf[NH][j][ks]

    const int NT = KDIM / 64;      // K-tiles (even; >=4 for both instantiations)
    const int NTP = NT / 2;        // tile pairs per block

    // prologue: tile0 (buf0) all 4 halves first, then tile1 (buf1) {A0,B1,A1}
    STAGE(0, 0, 0, Ab, 0);
    STAGE(0, 0, 1, Ab, 0);
    STAGE(0, 1, 0, Bb, 0);
    STAGE(0, 1, 1, Bb, 0);
    STAGE(1, 0, 0, Ab, 1);
    STAGE(1, 1, 1, Bb, 1);
    STAGE(1, 0, 1, Ab, 1);
    VM6();                          // tile0's 8 loads landed; 6 stay in flight
    BAR();

    for (int tp = 0; tp < NTP; tp++) {
        int t0 = 2 * tp;
        bool sB = (t0 + 2 < NT);    // stages for tile t0+2 (buf0)
        bool sC = (t0 + 3 < NT);    // stages for tile t0+3 (buf1)
        // ---- tile t0, buf 0 ----
        // P0
        FRAG_A(0, 0); FRAG_B(0, 0);
        STAGE(1, 1, 0, Bb, t0 + 1);
        LGKM8();
        BAR(); LGKM0(); MMAQ(0, 0); BAR();
        // P1
        FRAG_B(0, 1);
        if (sB) STAGE(0, 0, 0, Ab, t0 + 2);
        BAR(); LGKM0(); MMAQ(0, 1); BAR();
        // P2
        FRAG_A(0, 1);
        if (sB) STAGE(0, 1, 1, Bb, t0 + 2);
        BAR(); LGKM0(); MMAQ(1, 0); BAR();
        // P3
        if (sB) STAGE(0, 0, 1, Ab, t0 + 2);
        BAR(); LGKM0(); MMAQ(1, 1);
        if (sB) VM6(); else VM0();  // tile t0+1 fully landed
        BAR();
        // ---- tile t0+1, buf 1 ----
        // P4
        FRAG_A(1, 0); FRAG_B(1, 0);
        if (sB) STAGE(0, 1, 0, Bb, t0 + 2);
        LGKM8();
        BAR(); LGKM0(); MMAQ(0, 0); BAR();
        // P5
        FRAG_B(1, 1);
        if (sC) STAGE(1, 0, 0, Ab, t0 + 3);
        BAR(); LGKM0(); MMAQ(0, 1); BAR();
        // P6
        FRAG_A(1, 1);
        if (sC) STAGE(1, 1, 1, Bb, t0 + 3);
        BAR(); LGKM0(); MMAQ(1, 0); BAR();
        // P7
        if (sC) STAGE(1, 0, 1, Ab, t0 + 3);
        BAR(); LGKM0(); MMAQ(1, 1);
        if (sC) { VM6(); }          // tile t0+2 fully landed
        else if (sB) { VM0(); }
        BAR();
    }

    // epilogue; C/D layout: col = lane&15, row = (lane>>4)*4 + reg
    int cl = lane & 15, rq = (lane >> 4) << 2;
#pragma unroll
    for (int MH = 0; MH < 2; MH++)
#pragma unroll
    for (int i = 0; i < 4; i++)
#pragma unroll
    for (int NH = 0; NH < 2; NH++)
#pragma unroll
    for (int j = 0; j < 2; j++) {
        int gcol = col0 + NH * 128 + wn * 32 + j * 16 + cl;
        float b = bias[e * NDIM + gcol];
        int growb = row0 + MH * 128 + wm * 64 + i * 16 + rq;
#pragma unroll
        for (int r = 0; r < 4; r++) {
            int grow = growb + r;
            float v = acc[MH][i][NH][j][r] + b;
            if (EPI == 1) {
                v = 0.5f * v * (1.0f + erff(v * 0.70710678118654752f));  // exact gelu
                hg[(size_t)grow * NDIM + gcol] = f2bf(v);
            } else {
                int token = inv_row[grow];
                if (token >= 0) out[(size_t)token * NDIM + gcol] = rowprob[grow] * v;
            }
        }
    }
}

// ---------------------------------------------------------------------------
extern "C" void kernel_launch(void* const* d_in, const int* in_sizes, int n_in,
                              void* d_out, int out_size, void* d_ws, size_t ws_size,
                              hipStream_t stream) {
    const float* x  = (const float*)d_in[0];
    const float* Wr = (const float*)d_in[1];
    const float* br = (const float*)d_in[2];
    const float* W1 = (const float*)d_in[3];
    const float* b1 = (const float*)d_in[4];
    const float* W2 = (const float*)d_in[5];
    const float* b2 = (const float*)d_in[6];
    float* out = (float*)d_out;

    // workspace layout (~228.2 MB)
    char* ws = (char*)d_ws;
    unsigned short* W1t = (unsigned short*)ws;                        // [E][H][C] bf16, 64MB
    unsigned short* W2t = (unsigned short*)(ws + 67108864ull);        // [E][C][H] bf16, 64MB
    unsigned short* xg  = (unsigned short*)(ws + 134217728ull);       // [ROWS_PAD][C] bf16, 20MB
    unsigned short* hg  = (unsigned short*)(ws + 155189248ull);       // [ROWS_PAD][H] bf16, 80MB
    char* small = ws + 239075328ull;
    float* probs     = (float*)small;                        // 32KB
    int*   eidx      = (int*)(small + 32768);                // 32KB
    float* rowprob   = (float*)(small + 65536);              // 40KB
    int*   inv_row   = (int*)(small + 106496);               // 40KB
    int*   tok_row   = (int*)(small + 147456);               // 32KB
    int*   blk_cnt   = (int*)(small + 180224);               // 1KB
    int*   blockbase = blk_cnt + HBLK * E_NUM;               // 1KB
    int*   cnt       = blockbase + HBLK * E_NUM;             // 8
    int*   seg       = cnt + 8;                              // 8

    hipMemsetAsync(xg, 0, (size_t)ROWS_PAD * C_DIM * 2, stream);          // zero pads
    hipMemsetAsync(inv_row, 0xFF, ROWS_PAD * 4, stream);                  // -1

    // W1 [E][C][H] -> W1t [E][H][C] ; W2 [E][H][C] -> W2t [E][C][H]
    transpose_w<<<dim3(H_DIM / 64, C_DIM / 256, E_NUM), 256, 0, stream>>>(W1, W1t, C_DIM, H_DIM);
    transpose_w<<<dim3(C_DIM / 64, H_DIM / 256, E_NUM), 256, 0, stream>>>(W2, W2t, H_DIM, C_DIM);

    router_kernel<<<N_TOK / 4, 256, 0, stream>>>(x, Wr, br, probs, eidx);
    hist_kernel<<<HBLK, 256, 0, stream>>>(eidx, blk_cnt);
    finalize_kernel<<<1, 64, 0, stream>>>(blk_cnt, cnt, seg, blockbase,
                                          out + (size_t)N_TOK * C_DIM);
    gatherpos_kernel<<<HBLK, 256, 0, stream>>>(probs, eidx, blockbase, tok_row, inv_row, rowprob);
    copy_kernel<<<N_TOK / 4, 256, 0, stream>>>(x, tok_row, xg);

    // GEMM1: h = gelu(xg @ W1[e] + b1[e])   [rows x H], K=C
    moe_gemm<C_DIM, H_DIM, 1><<<dim3(H_DIM / 256, MT_MAX), 512, 0, stream>>>(
        xg, W1t, b1, hg, nullptr, cnt, seg, inv_row, rowprob);
    // GEMM2: out[token] = prob * (hg @ W2[e] + b2[e])   [rows x C], K=H
    moe_gemm<H_DIM, C_DIM, 2><<<dim3(C_DIM / 256, MT_MAX), 512, 0, stream>>>(
        hg, W2t, b2, nullptr, out, cnt, seg, inv_row, rowprob);
}